// Round 6
// baseline (134.405 us; speedup 1.0000x reference)
//
#include <hip/hip_runtime.h>
#include <stdint.h>

// ---------------------------------------------------------------------------
// B=2048, F0=40, D=32, LAYER0=LAYER1=128.  Rows r=b*32+d (65536).
//   phase0: h0[r,s] = relu(sum_{i<40,j<40} X[r,i]X[r,j] W0[i,j,s] + b0[s])
//   phase1: d1[r,s] = relu(sum_{i<40,j<64} X[r,i]NH[r,j] W1[i,j,s] + b1[s])
//   out[b,0:64] = sum_d h0[:,64:128]; out[b,64:192] = sum_d d1
//
// Round-6: OCCUPANCY.  Round-5 counters: MfmaUtil 37%, VALUBusy 24%, occ 20%
// -- grid 512 = 2 blocks/CU = 2 waves/SIMD caps matrix pipe at 43%
// (2 waves x 16 mfma x 19.4cyc = 620 of 1444 cyc/step wall).  Now: grid 1024
// blocks of 2 batches (M=64 rows), 4 waves, wave = 64r x 32s (acc[4][2],
// 8 MFMA/step).  No mw-split -> block's 8KB W-tile read ONCE per step, so
// chip L2 traffic is unchanged despite 2x blocks.  VGPR drops (acc 64->32)
// -> 4 waves/SIMD fits; 4 blocks/CU = 16 waves/CU (50% occ).
// FP16 datapath: A-frag = ONE v_pk_mul_f16 per pair (xi broadcast half2 *
// packed xj).  B streams from L2-resident Wp, prefetch 1 tile ahead; jv LDS
// reads pipelined 1 jc-chunk ahead.  No k-loop barriers.
// ---------------------------------------------------------------------------

typedef __attribute__((ext_vector_type(8))) _Float16 half8;
typedef __attribute__((ext_vector_type(2))) _Float16 half2v;
typedef __attribute__((ext_vector_type(4))) float f32x4;

__device__ __forceinline__ unsigned short f2h(float f) {   // v_cvt_f16_f32, RNE
    return __builtin_bit_cast(unsigned short, (_Float16)f);
}
__device__ __forceinline__ float qsum(float v) {  // reduce across row-quads
    v += __shfl_xor(v, 16, 64);
    v += __shfl_xor(v, 32, 64);
    return v;
}

// Permute W -> Wp[t][s][kl] fp16, t = jc*10+ic, kl = ii*8+jj, i=ic*4+ii,
// j=jc*8+jj.  One block per tile t; thread = (s, h) writes 32B contiguous.
__global__ void permute_w_both(const float* __restrict__ W0, const float* __restrict__ W1,
                               unsigned short* __restrict__ Wp0, unsigned short* __restrict__ Wp1)
{
    int t = blockIdx.x;
    int s = threadIdx.x >> 1, h = threadIdx.x & 1;
    const float* W; unsigned short* Wp; int JW, tt;
    if (t < 50) { W = W0; Wp = Wp0; JW = 40; tt = t; }
    else        { W = W1; Wp = Wp1; JW = 64; tt = t - 50; }
    int jc = tt / 10, ic = tt - jc * 10;
    unsigned short outv[16];
    #pragma unroll
    for (int q = 0; q < 16; ++q) {
        int kl = h * 16 + q;
        int i = ic * 4 + (kl >> 3), j = jc * 8 + (kl & 7);
        outv[q] = f2h(W[((size_t)(i * JW + j)) * 128 + s]);
    }
    unsigned short* dst = Wp + (size_t)tt * 4096 + s * 32 + h * 16;
    *(uint4*)dst       = *(const uint4*)outv;        // kl h*16+0..7
    *(uint4*)(dst + 8) = *(const uint4*)(outv + 8);  // kl h*16+8..15
}

// One GEMM phase, barrier-free.  NJC j-chunks x 10 i-chunks of k-tiles.
// Wave covers all 64 block-rows x its 32-s slice: acc[4][2].
template<int NJC>
__device__ __forceinline__ void gemm_phase_reg(
    const unsigned short* __restrict__ Wp,   // [NJC*10][128][32] fp16, global
    const unsigned short* __restrict__ Jl,   // LDS j-source (Xl or NH)
    int jstride,                             // row stride of Jl in elems
    const unsigned int xi2[4][10],           // broadcast half2 of X[r_mt, ic*4+kc]
    f32x4 acc[4][2], int tid)
{
    const int lane = tid & 63;
    const int nw = tid >> 6;                        // s-slice 0..3
    const int ml = lane & 15;
    const int kc = lane >> 4;                       // k-chunk == ii
    const unsigned short* wt = Wp + ((nw * 32 + ml) * 32 + kc * 8);
    const unsigned short* jrow[4];
    #pragma unroll
    for (int mt = 0; mt < 4; ++mt)
        jrow[mt] = Jl + (mt * 16 + ml) * jstride;

    uint4 bv[2];                                    // current B frags (tile 0)
    #pragma unroll
    for (int nt = 0; nt < 2; ++nt) bv[nt] = *(const uint4*)(wt + nt * 512);

    uint4 jv[4], jvn[4];                            // jc-chunk j-values (packed fp16)
    #pragma unroll
    for (int mt = 0; mt < 4; ++mt) jv[mt] = *(const uint4*)(jrow[mt]);

    for (int jc = 0; jc < NJC; ++jc) {
        if (jc + 1 < NJC) {                         // prefetch next jc's j-values
            #pragma unroll
            for (int mt = 0; mt < 4; ++mt) jvn[mt] = *(const uint4*)(jrow[mt] + (jc + 1) * 8);
        } else {
            #pragma unroll
            for (int mt = 0; mt < 4; ++mt) jvn[mt] = jv[mt];   // keep defined (dead)
        }
        #pragma unroll
        for (int ic = 0; ic < 10; ++ic) {
            // prefetch next tile's B frags (last-of-last reloads current: dead)
            const unsigned short* wn;
            if (ic < 9) wn = wt + 4096;
            else        wn = (jc + 1 < NJC) ? wt + 4096 : wt;
            uint4 bn[2];
            #pragma unroll
            for (int nt = 0; nt < 2; ++nt) bn[nt] = *(const uint4*)(wn + nt * 512);
            // A frags: one v_pk_mul_f16 per pair (xi broadcast * packed xj)
            uint4 av[4];
            #pragma unroll
            for (int mt = 0; mt < 4; ++mt) {
                half2v x2 = __builtin_bit_cast(half2v, xi2[mt][ic]);
                av[mt].x = __builtin_bit_cast(unsigned int,
                    (half2v)(x2 * __builtin_bit_cast(half2v, jv[mt].x)));
                av[mt].y = __builtin_bit_cast(unsigned int,
                    (half2v)(x2 * __builtin_bit_cast(half2v, jv[mt].y)));
                av[mt].z = __builtin_bit_cast(unsigned int,
                    (half2v)(x2 * __builtin_bit_cast(half2v, jv[mt].z)));
                av[mt].w = __builtin_bit_cast(unsigned int,
                    (half2v)(x2 * __builtin_bit_cast(half2v, jv[mt].w)));
            }
            #pragma unroll
            for (int mt = 0; mt < 4; ++mt)
                #pragma unroll
                for (int nt = 0; nt < 2; ++nt)
                    acc[mt][nt] = __builtin_amdgcn_mfma_f32_16x16x32_f16(
                        __builtin_bit_cast(half8, av[mt]),
                        __builtin_bit_cast(half8, bv[nt]),
                        acc[mt][nt], 0, 0, 0);
            #pragma unroll
            for (int nt = 0; nt < 2; ++nt) bv[nt] = bn[nt];
            wt = wn;
        }
        #pragma unroll
        for (int mt = 0; mt < 4; ++mt) jv[mt] = jvn[mt];
    }
}

__global__ __launch_bounds__(256, 4)
void fused_two_layer(const float* __restrict__ x,
                     const unsigned short* __restrict__ W0p,
                     const float* __restrict__ b0,
                     const unsigned short* __restrict__ W1p,
                     const float* __restrict__ b1,
                     float* __restrict__ out)
{
    __shared__ __align__(16) unsigned short Xl[64 * 40];  // [r][i] fp16, 80B rows
    __shared__ __align__(16) unsigned short NH[64 * 72];  // stride 72 (144B rows
        // walk all 32 banks for b128 reads; 128B stride would be 8-way)

    const int tid  = threadIdx.x;
    const int lane = tid & 63;
    const int nw   = tid >> 6;          // wave's s-slice (32 cols)
    const int ml   = lane & 15;
    const int kc   = lane >> 4;         // quad / k-chunk

    // ---- stage X: x[2b][i][d] fp32 -> Xl[(bl*32+d)*40 + i] fp16 (RNE) ----
    const float* xblk = x + (size_t)blockIdx.x * (2 * 40 * 32);
    #pragma unroll
    for (int bl = 0; bl < 2; ++bl) {
        #pragma unroll
        for (int k = 0; k < 5; ++k) {
            int e = 256 * k + tid;
            int i = e >> 5, d = e & 31;
            Xl[(bl * 32 + d) * 40 + i] = f2h(xblk[bl * 1280 + e]);
        }
    }
    __syncthreads();

    // ---- preload this lane's i-scalars as broadcast half2 (both phases) ----
    unsigned int xi2[4][10];
    #pragma unroll
    for (int mt = 0; mt < 4; ++mt) {
        const unsigned short* xr = Xl + (mt * 16 + ml) * 40;
        #pragma unroll
        for (int ic = 0; ic < 10; ++ic) {
            unsigned int u = xr[ic * 4 + kc];
            xi2[mt][ic] = u | (u << 16);
        }
    }

    f32x4 acc[4][2];
    const f32x4 zero4 = {0.f, 0.f, 0.f, 0.f};
    #pragma unroll
    for (int mt = 0; mt < 4; ++mt)
        #pragma unroll
        for (int nt = 0; nt < 2; ++nt) acc[mt][nt] = zero4;

    // ================= phase 0: 50 tiles, j from X =================
    gemm_phase_reg<5>(W0p, Xl, 40, xi2, acc, tid);

    {   // epilogue 0: bias+relu; nw<2 (s<64) -> NH; nw>=2 -> d-sum -> out[:,0:64]
        float bias[2];
        #pragma unroll
        for (int nt = 0; nt < 2; ++nt) bias[nt] = b0[nw * 32 + nt * 16 + ml];
        if (nw < 2) {
            #pragma unroll
            for (int mt = 0; mt < 4; ++mt) {
                int r = mt * 16 + (kc << 2);
                #pragma unroll
                for (int nt = 0; nt < 2; ++nt) {
                    int s = nw * 32 + nt * 16 + ml;
                    #pragma unroll
                    for (int rg = 0; rg < 4; ++rg) {
                        float v = fmaxf(acc[mt][nt][rg] + bias[nt], 0.0f);
                        NH[(r + rg) * 72 + s] = f2h(v);
                    }
                }
            }
        } else {
            int bb = blockIdx.x * 2;
            #pragma unroll
            for (int nt = 0; nt < 2; ++nt) {
                float sA = 0.f, sB = 0.f;
                #pragma unroll
                for (int rg = 0; rg < 4; ++rg) {
                    sA += fmaxf(acc[0][nt][rg] + bias[nt], 0.f) + fmaxf(acc[1][nt][rg] + bias[nt], 0.f);
                    sB += fmaxf(acc[2][nt][rg] + bias[nt], 0.f) + fmaxf(acc[3][nt][rg] + bias[nt], 0.f);
                }
                sA = qsum(sA); sB = qsum(sB);
                if (lane < 16) {
                    int col = (nw - 2) * 32 + nt * 16 + lane;
                    out[(size_t)bb * 192 + col]       = sA;
                    out[(size_t)(bb + 1) * 192 + col] = sB;
                }
            }
        }
    }
    __syncthreads();   // NH visible to all waves

    #pragma unroll
    for (int mt = 0; mt < 4; ++mt)
        #pragma unroll
        for (int nt = 0; nt < 2; ++nt) acc[mt][nt] = zero4;

    // ================= phase 1: 80 tiles, j from NH ================
    gemm_phase_reg<8>(W1p, NH, 72, xi2, acc, tid);

    {   // epilogue 1: bias+relu; d-sum -> out[:, 64:192]
        float bias[2];
        #pragma unroll
        for (int nt = 0; nt < 2; ++nt) bias[nt] = b1[nw * 32 + nt * 16 + ml];
        int bb = blockIdx.x * 2;
        #pragma unroll
        for (int nt = 0; nt < 2; ++nt) {
            float sA = 0.f, sB = 0.f;
            #pragma unroll
            for (int rg = 0; rg < 4; ++rg) {
                sA += fmaxf(acc[0][nt][rg] + bias[nt], 0.f) + fmaxf(acc[1][nt][rg] + bias[nt], 0.f);
                sB += fmaxf(acc[2][nt][rg] + bias[nt], 0.f) + fmaxf(acc[3][nt][rg] + bias[nt], 0.f);
            }
            sA = qsum(sA); sB = qsum(sB);
            if (lane < 16) {
                int col = 64 + nw * 32 + nt * 16 + lane;
                out[(size_t)bb * 192 + col]       = sA;
                out[(size_t)(bb + 1) * 192 + col] = sB;
            }
        }
    }
}

extern "C" void kernel_launch(void* const* d_in, const int* in_sizes, int n_in,
                              void* d_out, int out_size, void* d_ws, size_t ws_size,
                              hipStream_t stream) {
    const float* x  = (const float*)d_in[0];   // [2048][40][32]
    const float* W0 = (const float*)d_in[1];   // [40][40][128]
    const float* b0 = (const float*)d_in[2];   // [128]
    const float* W1 = (const float*)d_in[3];   // [40][64][128]
    const float* b1 = (const float*)d_in[4];   // [128]
    float* out = (float*)d_out;                // [2048][192]

    unsigned short* W0p = (unsigned short*)d_ws;                          // 50*4096*2 = 409600 B
    unsigned short* W1p = (unsigned short*)((char*)d_ws + 50 * 4096 * 2); // 80*4096*2 = 655360 B

    permute_w_both<<<130, 256, 0, stream>>>(W0, W1, W0p, W1p);
    fused_two_layer<<<1024, 256, 0, stream>>>(x, W0p, b0, W1p, b1, out);
}

// Round 7
// 131.350 us; speedup vs baseline: 1.0233x; 1.0233x over previous
//
#include <hip/hip_runtime.h>
#include <stdint.h>

// ---------------------------------------------------------------------------
// B=2048, F0=40, D=32, LAYER0=LAYER1=128.  Rows r=b*32+d (65536).
//   phase0: h0[r,s] = relu(sum_{i<40,j<40} X[r,i]X[r,j] W0[i,j,s] + b0[s])
//   phase1: d1[r,s] = relu(sum_{i<40,j<64} X[r,i]NH[r,j] W1[i,j,s] + b1[s])
//   out[b,0:64] = sum_d h0[:,64:128]; out[b,64:192] = sum_d d1
//
// Round-7: W THROUGH LDS.  Rounds 5/6 invariant: 32KB/CU/step of W-fragment
// reads from L2 @ ~21B/cyc = the 1532-cyc wall (MfmaUtil pinned 36% while
// occupancy doubled 20->39%) -> pure-L2 streaming is the bottleneck, not
// latency or waves.  Fix: stage each 8KB W-tile in LDS ONCE per block and
// share across waves; amortize over more rows: grid 256 x 512 thr, M=256
// rows (8 batches), 8 waves = 4 row-tiles x 2 s-halves, acc[4][4].
// Staging: global->reg (tile t+2) -> ds_write (t+1), double-buffered Wb,
// one barrier per k-step.  Per-CU/step: MFMA 620cyc (limiter), LDS ~490
// (B-reads uniform 8/bank = conflict-free), VMEM 8KB=380cyc (4x cut).
// FP16 datapath: A-frag = one v_pk_mul_f16 per pair (xi2 broadcast * packed
// jv); jv LDS reads pipelined one jc-chunk ahead.
// ---------------------------------------------------------------------------

typedef __attribute__((ext_vector_type(8))) _Float16 half8;
typedef __attribute__((ext_vector_type(2))) _Float16 half2v;
typedef __attribute__((ext_vector_type(4))) float f32x4;

__device__ __forceinline__ unsigned short f2h(float f) {   // v_cvt_f16_f32, RNE
    return __builtin_bit_cast(unsigned short, (_Float16)f);
}
__device__ __forceinline__ float qsum(float v) {  // reduce across row-quads
    v += __shfl_xor(v, 16, 64);
    v += __shfl_xor(v, 32, 64);
    return v;
}

// Permute W -> Wp[t][s][kl] fp16, t = jc*10+ic, kl = ii*8+jj, i=ic*4+ii,
// j=jc*8+jj.  One block per tile t; thread = (s, h) writes 32B contiguous.
__global__ void permute_w_both(const float* __restrict__ W0, const float* __restrict__ W1,
                               unsigned short* __restrict__ Wp0, unsigned short* __restrict__ Wp1)
{
    int t = blockIdx.x;
    int s = threadIdx.x >> 1, h = threadIdx.x & 1;
    const float* W; unsigned short* Wp; int JW, tt;
    if (t < 50) { W = W0; Wp = Wp0; JW = 40; tt = t; }
    else        { W = W1; Wp = Wp1; JW = 64; tt = t - 50; }
    int jc = tt / 10, ic = tt - jc * 10;
    unsigned short outv[16];
    #pragma unroll
    for (int q = 0; q < 16; ++q) {
        int kl = h * 16 + q;
        int i = ic * 4 + (kl >> 3), j = jc * 8 + (kl & 7);
        outv[q] = f2h(W[((size_t)(i * JW + j)) * 128 + s]);
    }
    unsigned short* dst = Wp + (size_t)tt * 4096 + s * 32 + h * 16;
    *(uint4*)dst       = *(const uint4*)outv;        // kl h*16+0..7
    *(uint4*)(dst + 8) = *(const uint4*)(outv + 8);  // kl h*16+8..15
}

// One GEMM phase.  NJC j-chunks x 10 i-chunks of k-tiles; W tile staged in
// LDS (double-buffered), one barrier per step.
template<int NJC>
__device__ __forceinline__ void gemm_phase(
    const unsigned short* __restrict__ Wp,   // [NJC*10][128][32] fp16, global
    const unsigned short* __restrict__ Jl,   // LDS j-source (Xl or NH)
    int jstride,                             // row stride of Jl in elems
    const unsigned int xi2[4][10],           // broadcast half2 of X[r, ic*4+kc]
    unsigned short* Wb,                      // LDS W double buffer [2][4096]
    f32x4 acc[4][4], int tid)
{
    constexpr int T = NJC * 10;
    const int lane = tid & 63;
    const int rt = (tid >> 6) & 3;           // row-tile (64 rows)
    const int sh = tid >> 8;                 // s-half (64 cols)
    const int ml = lane & 15;
    const int kc = lane >> 4;                // quad == k-chunk == ii

    const unsigned short* jrow[4];
    #pragma unroll
    for (int mt = 0; mt < 4; ++mt)
        jrow[mt] = Jl + (rt * 64 + mt * 16 + ml) * jstride;

    const unsigned short* brd = Wb + (sh * 64 + ml) * 32 + kc * 8;  // +nt*512, +cb*4096
    unsigned short* bwr = Wb + tid * 8;      // staging slice (identity layout)

    // prime: tile 0 -> Wb[0]; tile 1 -> regs
    uint4 wrn;
    {
        uint4 w0 = *(const uint4*)(Wp + tid * 8);
        *(uint4*)bwr = w0;
        wrn = *(const uint4*)(Wp + 4096 + tid * 8);
    }
    uint4 jv[4], jvn[4];
    #pragma unroll
    for (int mt = 0; mt < 4; ++mt) jv[mt] = *(const uint4*)(jrow[mt]);
    __syncthreads();

    for (int jc = 0; jc < NJC; ++jc) {
        if (jc + 1 < NJC) {                  // prefetch next jc's j-values
            #pragma unroll
            for (int mt = 0; mt < 4; ++mt) jvn[mt] = *(const uint4*)(jrow[mt] + (jc + 1) * 8);
        } else {
            #pragma unroll
            for (int mt = 0; mt < 4; ++mt) jvn[mt] = jv[mt];   // dead, keep defined
        }
        #pragma unroll
        for (int ic = 0; ic < 10; ++ic) {
            const int tt = jc * 10 + ic;
            const int cb = ic & 1;           // == tt&1 (jc*10 even)
            const int nb = cb ^ 1;
            // stage tile tt+1 (in regs since step tt-1) into the other buffer
            if (tt + 1 < T) *(uint4*)(bwr + nb * 4096) = wrn;
            // prefetch tile tt+2 into regs (guard: dead reload of current)
            {
                const unsigned short* wg =
                    Wp + (size_t)((tt + 2 < T) ? (tt + 2) : tt) * 4096 + tid * 8;
                wrn = *(const uint4*)wg;
            }
            // B frags from LDS (uniform 8 accesses/bank -> conflict-free)
            uint4 bv[4];
            #pragma unroll
            for (int nt = 0; nt < 4; ++nt)
                bv[nt] = *(const uint4*)(brd + cb * 4096 + nt * 512);
            // A frags: one v_pk_mul_f16 per pair
            uint4 av[4];
            #pragma unroll
            for (int mt = 0; mt < 4; ++mt) {
                half2v x2 = __builtin_bit_cast(half2v, xi2[mt][ic]);
                av[mt].x = __builtin_bit_cast(unsigned int,
                    (half2v)(x2 * __builtin_bit_cast(half2v, jv[mt].x)));
                av[mt].y = __builtin_bit_cast(unsigned int,
                    (half2v)(x2 * __builtin_bit_cast(half2v, jv[mt].y)));
                av[mt].z = __builtin_bit_cast(unsigned int,
                    (half2v)(x2 * __builtin_bit_cast(half2v, jv[mt].z)));
                av[mt].w = __builtin_bit_cast(unsigned int,
                    (half2v)(x2 * __builtin_bit_cast(half2v, jv[mt].w)));
            }
            #pragma unroll
            for (int mt = 0; mt < 4; ++mt)
                #pragma unroll
                for (int nt = 0; nt < 4; ++nt)
                    acc[mt][nt] = __builtin_amdgcn_mfma_f32_16x16x32_f16(
                        __builtin_bit_cast(half8, av[mt]),
                        __builtin_bit_cast(half8, bv[nt]),
                        acc[mt][nt], 0, 0, 0);
            __syncthreads();                 // nb-writes visible; cb reads done
        }
        #pragma unroll
        for (int mt = 0; mt < 4; ++mt) jv[mt] = jvn[mt];
    }
}

__global__ __launch_bounds__(512, 2)
void fused_two_layer(const float* __restrict__ x,
                     const unsigned short* __restrict__ W0p,
                     const float* __restrict__ b0,
                     const unsigned short* __restrict__ W1p,
                     const float* __restrict__ b1,
                     float* __restrict__ out)
{
    __shared__ __align__(16) unsigned short Xl[256 * 40];   // 20.0 KB
    __shared__ __align__(16) unsigned short NH[256 * 72];   // 36.9 KB (stride 72
        // -> 144B rows: b128 j-reads walk banks 2-way max = free)
    __shared__ __align__(16) unsigned short Wb[2 * 4096];   // 16.0 KB W dbuf

    const int tid  = threadIdx.x;
    const int lane = tid & 63;
    const int rt   = (tid >> 6) & 3;    // row-tile (64 rows)
    const int sh   = tid >> 8;          // s-half (64 cols)
    const int ml   = lane & 15;
    const int kc   = lane >> 4;

    // ---- stage X: x[8b][i][d] fp32 -> Xl[(bl*32+d)*40 + i] fp16 (RNE) ----
    const float* xblk = x + (size_t)blockIdx.x * (8 * 40 * 32);
    #pragma unroll
    for (int bl = 0; bl < 8; ++bl) {
        #pragma unroll
        for (int k = 0; k < 3; ++k) {
            int f = 512 * k + tid;
            if (f < 1280) {
                int i = f >> 5, d = f & 31;
                Xl[(bl * 32 + d) * 40 + i] = f2h(xblk[bl * 1280 + f]);
            }
        }
    }
    __syncthreads();

    // ---- preload this lane's i-scalars as broadcast half2 (both phases) ----
    unsigned int xi2[4][10];
    #pragma unroll
    for (int mt = 0; mt < 4; ++mt) {
        const unsigned short* xr = Xl + (rt * 64 + mt * 16 + ml) * 40;
        #pragma unroll
        for (int ic = 0; ic < 10; ++ic) {
            unsigned int u = xr[ic * 4 + kc];
            xi2[mt][ic] = u | (u << 16);
        }
    }

    f32x4 acc[4][4];
    const f32x4 zero4 = {0.f, 0.f, 0.f, 0.f};
    #pragma unroll
    for (int mt = 0; mt < 4; ++mt)
        #pragma unroll
        for (int nt = 0; nt < 4; ++nt) acc[mt][nt] = zero4;

    // ================= phase 0: 50 tiles, j from X =================
    gemm_phase<5>(W0p, Xl, 40, xi2, Wb, acc, tid);

    {   // epilogue 0: bias+relu; sh==0 (s<64) -> NH; sh==1 -> d-sum -> out[:,0:64]
        float bias[4];
        #pragma unroll
        for (int nt = 0; nt < 4; ++nt) bias[nt] = b0[sh * 64 + nt * 16 + ml];
        if (sh == 0) {
            #pragma unroll
            for (int mt = 0; mt < 4; ++mt) {
                int r = rt * 64 + mt * 16 + (kc << 2);
                #pragma unroll
                for (int nt = 0; nt < 4; ++nt) {
                    int s = nt * 16 + ml;
                    #pragma unroll
                    for (int rg = 0; rg < 4; ++rg) {
                        float v = fmaxf(acc[mt][nt][rg] + bias[nt], 0.0f);
                        NH[(r + rg) * 72 + s] = f2h(v);
                    }
                }
            }
        } else {
            int bb = blockIdx.x * 8 + rt * 2;
            #pragma unroll
            for (int nt = 0; nt < 4; ++nt) {
                float sA = 0.f, sB = 0.f;
                #pragma unroll
                for (int rg = 0; rg < 4; ++rg) {
                    sA += fmaxf(acc[0][nt][rg] + bias[nt], 0.f) + fmaxf(acc[1][nt][rg] + bias[nt], 0.f);
                    sB += fmaxf(acc[2][nt][rg] + bias[nt], 0.f) + fmaxf(acc[3][nt][rg] + bias[nt], 0.f);
                }
                sA = qsum(sA); sB = qsum(sB);
                if (lane < 16) {
                    int col = nt * 16 + lane;        // s-64
                    out[(size_t)bb * 192 + col]       = sA;
                    out[(size_t)(bb + 1) * 192 + col] = sB;
                }
            }
        }
    }
    __syncthreads();   // NH visible to all waves

    #pragma unroll
    for (int mt = 0; mt < 4; ++mt)
        #pragma unroll
        for (int nt = 0; nt < 4; ++nt) acc[mt][nt] = zero4;

    // ================= phase 1: 80 tiles, j from NH ================
    gemm_phase<8>(W1p, NH, 72, xi2, Wb, acc, tid);

    {   // epilogue 1: bias+relu; d-sum -> out[:, 64:192]
        float bias[4];
        #pragma unroll
        for (int nt = 0; nt < 4; ++nt) bias[nt] = b1[sh * 64 + nt * 16 + ml];
        int bb = blockIdx.x * 8 + rt * 2;
        #pragma unroll
        for (int nt = 0; nt < 4; ++nt) {
            float sA = 0.f, sB = 0.f;
            #pragma unroll
            for (int rg = 0; rg < 4; ++rg) {
                sA += fmaxf(acc[0][nt][rg] + bias[nt], 0.f) + fmaxf(acc[1][nt][rg] + bias[nt], 0.f);
                sB += fmaxf(acc[2][nt][rg] + bias[nt], 0.f) + fmaxf(acc[3][nt][rg] + bias[nt], 0.f);
            }
            sA = qsum(sA); sB = qsum(sB);
            if (lane < 16) {
                int col = 64 + sh * 64 + nt * 16 + lane;
                out[(size_t)bb * 192 + col]       = sA;
                out[(size_t)(bb + 1) * 192 + col] = sB;
            }
        }
    }
}

extern "C" void kernel_launch(void* const* d_in, const int* in_sizes, int n_in,
                              void* d_out, int out_size, void* d_ws, size_t ws_size,
                              hipStream_t stream) {
    const float* x  = (const float*)d_in[0];   // [2048][40][32]
    const float* W0 = (const float*)d_in[1];   // [40][40][128]
    const float* b0 = (const float*)d_in[2];   // [128]
    const float* W1 = (const float*)d_in[3];   // [40][64][128]
    const float* b1 = (const float*)d_in[4];   // [128]
    float* out = (float*)d_out;                // [2048][192]

    unsigned short* W0p = (unsigned short*)d_ws;                          // 50*4096*2 = 409600 B
    unsigned short* W1p = (unsigned short*)((char*)d_ws + 50 * 4096 * 2); // 80*4096*2 = 655360 B

    permute_w_both<<<130, 256, 0, stream>>>(W0, W1, W0p, W1p);
    fused_two_layer<<<256, 512, 0, stream>>>(x, W0p, b0, W1p, b1, out);
}